// Round 2
// baseline (141.429 us; speedup 1.0000x reference)
//
#include <hip/hip_runtime.h>

#define INF_AREA 100000000.0f
#define BACKGROUND_LBL 80
#define MAX_GTS 512

__global__ __launch_bounds__(256) void fcos_target_kernel(
    const float* __restrict__ points,
    const float* __restrict__ regress_ranges,
    const float* __restrict__ strides_pts,
    const float* __restrict__ gt_bboxes,
    const int*   __restrict__ gt_labels,
    float* __restrict__ out,
    int N, int M)
{
    __shared__ float sb0[MAX_GTS], sb1[MAX_GTS], sb2[MAX_GTS], sb3[MAX_GTS];
    __shared__ float sarea[MAX_GTS], scx[MAX_GTS], scy[MAX_GTS];
    __shared__ int   slab[MAX_GTS];

    // Cooperative stage of all GT data into LDS (SoA).
    for (int j = threadIdx.x; j < M; j += blockDim.x) {
        float b0 = gt_bboxes[j * 4 + 0];
        float b1 = gt_bboxes[j * 4 + 1];
        float b2 = gt_bboxes[j * 4 + 2];
        float b3 = gt_bboxes[j * 4 + 3];
        sb0[j] = b0; sb1[j] = b1; sb2[j] = b2; sb3[j] = b3;
        sarea[j] = (b2 - b0) * (b3 - b1);
        scx[j]   = (b0 + b2) * 0.5f;
        scy[j]   = (b1 + b3) * 0.5f;
        slab[j]  = gt_labels[j];
    }
    __syncthreads();

    int i = blockIdx.x * blockDim.x + threadIdx.x;
    if (i >= N) return;

    float x   = points[i * 2 + 0];
    float y   = points[i * 2 + 1];
    float rr0 = regress_ranges[i * 2 + 0];
    float rr1 = regress_ranges[i * 2 + 1];
    float rad = strides_pts[i];

    float minA  = INF_AREA;
    int   minIdx = 0;

    for (int j = 0; j < M; ++j) {
        float b0 = sb0[j], b1 = sb1[j], b2 = sb2[j], b3 = sb3[j];
        // bbox targets
        float l = x - b0, t = y - b1, r = b2 - x, b = b3 - y;
        float mr = fmaxf(fmaxf(l, t), fmaxf(r, b));
        bool in_range = (mr >= rr0) && (mr <= rr1);
        // center-sampling box
        float cx = scx[j], cy = scy[j];
        float x0 = fmaxf(cx - rad, b0);
        float y0 = fmaxf(cy - rad, b1);
        float x1 = fminf(cx + rad, b2);
        float y1 = fminf(cy + rad, b3);
        float cmin = fminf(fminf(x - x0, y - y0), fminf(x1 - x, y1 - y));
        bool inside = cmin > 0.0f;
        float a = (in_range && inside) ? sarea[j] : INF_AREA;
        // strict '<' keeps FIRST occurrence of the minimum (jnp.argmin semantics)
        if (a < minA) { minA = a; minIdx = j; }
    }

    float b0 = sb0[minIdx], b1 = sb1[minIdx], b2 = sb2[minIdx], b3 = sb3[minIdx];
    int lab = (minA == INF_AREA) ? BACKGROUND_LBL : slab[minIdx];

    // Output layout: labels(N) | bbox_targets(N*4) | label_weights(N), all as float32.
    out[i] = (float)lab;
    float* bt = out + N + (size_t)i * 4;
    bt[0] = x - b0;
    bt[1] = y - b1;
    bt[2] = b2 - x;
    bt[3] = b3 - y;
    out[N + 4 * N + i] = 1.0f;
}

extern "C" void kernel_launch(void* const* d_in, const int* in_sizes, int n_in,
                              void* d_out, int out_size, void* d_ws, size_t ws_size,
                              hipStream_t stream) {
    const float* points         = (const float*)d_in[0];
    const float* regress_ranges = (const float*)d_in[1];
    const float* strides_pts    = (const float*)d_in[2];
    const float* gt_bboxes      = (const float*)d_in[3];
    const int*   gt_labels      = (const int*)d_in[4];
    float* out = (float*)d_out;

    int N = in_sizes[0] / 2;   // points is (N,2)
    int M = in_sizes[3] / 4;   // gt_bboxes is (M,4)

    int block = 256;
    int grid  = (N + block - 1) / block;
    fcos_target_kernel<<<grid, block, 0, stream>>>(
        points, regress_ranges, strides_pts, gt_bboxes, gt_labels, out, N, M);
}

// Round 3
// 73.581 us; speedup vs baseline: 1.9221x; 1.9221x over previous
//
#include <hip/hip_runtime.h>

#define INF_AREA 100000000.0f
#define BACKGROUND_LBL 80
#define MAX_GTS 512
#define SPLIT 8   // threads per point, each scans M/SPLIT GTs

__global__ __launch_bounds__(256) void fcos_target_kernel(
    const float* __restrict__ points,
    const float* __restrict__ regress_ranges,
    const float* __restrict__ strides_pts,
    const float* __restrict__ gt_bboxes,
    const int*   __restrict__ gt_labels,
    float* __restrict__ out,
    int N, int M)
{
    __shared__ float4 sbox[MAX_GTS];   // b0,b1,b2,b3
    __shared__ float4 saux[MAX_GTS];   // area, cx, cy, label(bit-cast)

    // Cooperative stage of all GT data into LDS (vectorized, SoA-of-float4).
    const float4* gtb4 = reinterpret_cast<const float4*>(gt_bboxes);
    for (int j = threadIdx.x; j < M; j += blockDim.x) {
        float4 b = gtb4[j];
        sbox[j] = b;
        float4 aux;
        aux.x = (b.z - b.x) * (b.w - b.y);   // area
        aux.y = (b.x + b.z) * 0.5f;          // cx
        aux.z = (b.y + b.w) * 0.5f;          // cy
        aux.w = __int_as_float(gt_labels[j]);
        saux[j] = aux;
    }
    __syncthreads();

    int tid = blockIdx.x * blockDim.x + threadIdx.x;
    int i   = tid >> 3;          // point index
    int sub = tid & (SPLIT - 1); // GT-dimension slice (adjacent lanes)
    if (i >= N) return;

    float x   = points[i * 2 + 0];
    float y   = points[i * 2 + 1];
    float rr0 = regress_ranges[i * 2 + 0];
    float rr1 = regress_ranges[i * 2 + 1];
    float rad = strides_pts[i];

    float minA   = INF_AREA;
    int   minIdx = sub;   // sub==0 thread starts at global index 0 (argmin-of-all-INF case)

    // Interleaved slice: wave's 8 distinct float4 slots per iter span all 32 banks,
    // 8-way same-address broadcast is free -> conflict-free ds_read_b128.
    for (int j = sub; j < M; j += SPLIT) {
        float4 bx = sbox[j];
        float4 ax = saux[j];
        float l = x - bx.x, t = y - bx.y, r = bx.z - x, b = bx.w - y;
        float mr = fmaxf(fmaxf(l, t), fmaxf(r, b));
        bool in_range = (mr >= rr0) && (mr <= rr1);
        float x0 = fmaxf(ax.y - rad, bx.x);
        float y0 = fmaxf(ax.z - rad, bx.y);
        float x1 = fminf(ax.y + rad, bx.z);
        float y1 = fminf(ax.z + rad, bx.w);
        float cmin = fminf(fminf(x - x0, y - y0), fminf(x1 - x, y1 - y));
        float a = (in_range && (cmin > 0.0f)) ? ax.x : INF_AREA;
        // strict '<' keeps the lowest j among ties within this thread's ascending scan
        if (a < minA) { minA = a; minIdx = j; }
    }

    // Reduce across the 8 slices (lanes for one point are adjacent: xor 1,2,4 stays in-group).
    // Tie-break on smaller global index reproduces jnp.argmin first-occurrence semantics.
    for (int off = 1; off < SPLIT; off <<= 1) {
        float oA = __shfl_xor(minA, off);
        int   oI = __shfl_xor(minIdx, off);
        if (oA < minA || (oA == minA && oI < minIdx)) { minA = oA; minIdx = oI; }
    }

    if (sub == 0) {
        float4 bb = sbox[minIdx];
        int lab = (minA == INF_AREA) ? BACKGROUND_LBL : __float_as_int(saux[minIdx].w);
        // Output layout: labels(N) | bbox_targets(N*4) | label_weights(N), all float32.
        out[i] = (float)lab;
        float* bt = out + N + (size_t)i * 4;
        bt[0] = x - bb.x;
        bt[1] = y - bb.y;
        bt[2] = bb.z - x;
        bt[3] = bb.w - y;
        out[5 * N + i] = 1.0f;
    }
}

extern "C" void kernel_launch(void* const* d_in, const int* in_sizes, int n_in,
                              void* d_out, int out_size, void* d_ws, size_t ws_size,
                              hipStream_t stream) {
    const float* points         = (const float*)d_in[0];
    const float* regress_ranges = (const float*)d_in[1];
    const float* strides_pts    = (const float*)d_in[2];
    const float* gt_bboxes      = (const float*)d_in[3];
    const int*   gt_labels      = (const int*)d_in[4];
    float* out = (float*)d_out;

    int N = in_sizes[0] / 2;   // points is (N,2)
    int M = in_sizes[3] / 4;   // gt_bboxes is (M,4)

    int block = 256;
    long long total = (long long)N * SPLIT;
    int grid = (int)((total + block - 1) / block);
    fcos_target_kernel<<<grid, block, 0, stream>>>(
        points, regress_ranges, strides_pts, gt_bboxes, gt_labels, out, N, M);
}

// Round 4
// 72.252 us; speedup vs baseline: 1.9574x; 1.0184x over previous
//
#include <hip/hip_runtime.h>

#define INF_AREA 100000000.0f
#define BACKGROUND_LBL 80
#define MAX_GTS 512
#define SPLIT 32   // threads per point, each scans M/SPLIT GTs

__global__ __launch_bounds__(256) void fcos_target_kernel(
    const float* __restrict__ points,
    const float* __restrict__ regress_ranges,
    const float* __restrict__ strides_pts,
    const float* __restrict__ gt_bboxes,
    const int*   __restrict__ gt_labels,
    float* __restrict__ out,
    int N, int M)
{
    // Only the raw boxes live in LDS (8 KB -> no LDS occupancy limit).
    // area/cx/cy are recomputed inline (~6 VALU/pair, cheaper than 16B/pair LDS reads).
    __shared__ float4 sbox[MAX_GTS];

    const float4* gtb4 = reinterpret_cast<const float4*>(gt_bboxes);
    for (int j = threadIdx.x; j < M; j += blockDim.x)
        sbox[j] = gtb4[j];
    __syncthreads();

    int tid = blockIdx.x * blockDim.x + threadIdx.x;
    int i   = tid >> 5;          // point index (32 consecutive threads per point)
    int sub = tid & (SPLIT - 1); // GT-dimension slice
    if (i >= N) return;

    float x   = points[i * 2 + 0];
    float y   = points[i * 2 + 1];
    float rr0 = regress_ranges[i * 2 + 0];
    float rr1 = regress_ranges[i * 2 + 1];
    float rad = strides_pts[i];

    float minA   = INF_AREA;
    int   minIdx = sub;   // thread sub==0 starts at 0 -> all-INF row argmin = 0, like jnp

    #pragma unroll 4
    for (int j = sub; j < M; j += SPLIT) {
        float4 bx = sbox[j];
        float l = x - bx.x, t = y - bx.y, r = bx.z - x, b = bx.w - y;
        float mr = fmaxf(fmaxf(l, t), fmaxf(r, b));
        bool in_range = (mr >= rr0) && (mr <= rr1);
        float cx = (bx.x + bx.z) * 0.5f;
        float cy = (bx.y + bx.w) * 0.5f;
        float x0 = fmaxf(cx - rad, bx.x);
        float y0 = fmaxf(cy - rad, bx.y);
        float x1 = fminf(cx + rad, bx.z);
        float y1 = fminf(cy + rad, bx.w);
        float cmin = fminf(fminf(x - x0, y - y0), fminf(x1 - x, y1 - y));
        float a = (in_range && (cmin > 0.0f)) ? (bx.z - bx.x) * (bx.w - bx.y) : INF_AREA;
        // strict '<' keeps the lowest j among ties within this thread's ascending scan
        if (a < minA) { minA = a; minIdx = j; }
    }

    // Reduce across 32 slices; lanes for one point are 32 consecutive lanes, so
    // xor offsets 1..16 stay inside the group. Tie-break on smaller global index
    // reproduces jnp.argmin first-occurrence semantics.
    for (int off = 1; off < SPLIT; off <<= 1) {
        float oA = __shfl_xor(minA, off);
        int   oI = __shfl_xor(minIdx, off);
        if (oA < minA || (oA == minA && oI < minIdx)) { minA = oA; minIdx = oI; }
    }

    if (sub == 0) {
        float4 bb = sbox[minIdx];
        int lab = (minA == INF_AREA) ? BACKGROUND_LBL : gt_labels[minIdx];
        // Output layout: labels(N) | bbox_targets(N*4) | label_weights(N), all float32.
        out[i] = (float)lab;
        float4 bt = make_float4(x - bb.x, y - bb.y, bb.z - x, bb.w - y);
        *reinterpret_cast<float4*>(out + N + (size_t)i * 4) = bt;
        out[5 * (size_t)N + i] = 1.0f;
    }
}

extern "C" void kernel_launch(void* const* d_in, const int* in_sizes, int n_in,
                              void* d_out, int out_size, void* d_ws, size_t ws_size,
                              hipStream_t stream) {
    const float* points         = (const float*)d_in[0];
    const float* regress_ranges = (const float*)d_in[1];
    const float* strides_pts    = (const float*)d_in[2];
    const float* gt_bboxes      = (const float*)d_in[3];
    const int*   gt_labels      = (const int*)d_in[4];
    float* out = (float*)d_out;

    int N = in_sizes[0] / 2;   // points is (N,2)
    int M = in_sizes[3] / 4;   // gt_bboxes is (M,4)

    int block = 256;
    long long total = (long long)N * SPLIT;
    int grid = (int)((total + block - 1) / block);
    fcos_target_kernel<<<grid, block, 0, stream>>>(
        points, regress_ranges, strides_pts, gt_bboxes, gt_labels, out, N, M);
}